// Round 2
// baseline (1034.187 us; speedup 1.0000x reference)
//
#include <hip/hip_runtime.h>
#include <hip/hip_bf16.h>

// GEMM: out[256,1000] = X[256,150528] * C[1000,150528]^T  (fp32 in/out)
// R4: depth-2 register staging + raw lgkm-only barriers (loads stay in flight
// across barriers, counted vmcnt via compiler reg-deps), XOR-swizzled bf16 LDS
// (conflict-free ds_read_b128, no pad). BM=256 BN=128 BK=32, 8 waves, SPLIT=96.

#define BM 256
#define BN 128
#define BK 32
#define SPLIT 96
#define NCLS 1000
#define DIM 150528
#define DCHUNK (DIM / SPLIT)  // 1568
#define KITERS (DCHUNK / BK)  // 49 exact

typedef short bf16x8 __attribute__((ext_vector_type(8)));
typedef float f32x4 __attribute__((ext_vector_type(4)));

static __device__ __forceinline__ unsigned short f2bf(float f) {
    union { __hip_bfloat16 h; unsigned short u; } cv;
    cv.h = __float2bfloat16(f);
    return cv.u;
}

__global__ __launch_bounds__(512, 2) void classifier_gemm(
    const float* __restrict__ X, const float* __restrict__ W,
    float* __restrict__ out)
{
    // bf16 tiles, XOR-swizzled (no pad): row = 32 bf16 = 64 B = 4 chunks of 16 B.
    // chunk c of row r stored at c ^ (r & 3).  As 32 KB + Bs 16 KB = 48 KB.
    __shared__ __align__(16) unsigned short As[2][BM * BK];
    __shared__ __align__(16) unsigned short Bs[2][BN * BK];

    const int t    = threadIdx.x;
    const int lane = t & 63;
    const int wave = t >> 6;      // 0..7
    const int wm   = wave >> 1;   // 0..3 (M quarter: 64 rows)
    const int wn   = wave & 1;    // 0..1 (N half: 64 cols)

    const int bj   = blockIdx.x;  // N tile: 0..7
    const int s    = blockIdx.y;  // D chunk: 0..95
    const int col0 = bj * BN;
    const size_t d0 = (size_t)s * DCHUNK;

    // staging map: 8 lanes cover one 32-float row segment (16 B each)
    const int frow = t >> 3;        // 0..63
    const int fcol = (t & 7) * 4;   // float offset in row

    const float* aptr = X + (size_t)frow * DIM + d0 + fcol;   // rows frow+64k, k=0..3
    const float* bptr0;                                       // row col0+frow  (<=959, in range)
    const float* bptr1;                                       // row col0+64+frow (clamped)
    {
        const int br0 = col0 + frow;
        int br1 = col0 + 64 + frow;
        if (br1 >= NCLS) br1 = NCLS - 1;   // garbage cols >=1000 never stored
        bptr0 = W + (size_t)br0 * DIM + d0 + fcol;
        bptr1 = W + (size_t)br1 * DIM + d0 + fcol;
    }

    // ---- swizzled LDS offsets (ushort units) ----
    // write: lane covers floats [4*(t&7), +4) of row r=frow+64k -> half h=t&1 of
    // chunk c=(t&7)>>1, stored at chunk c ^ (r&3) ( (frow+64k)&3 == frow&3 ).
    const int wsw = ((((t & 7) >> 1) ^ (frow & 3)) << 3) + (t & 1) * 4;
    const int wA  = frow * 32 + wsw;           // + k*2048 per 64-row group
    // read: frag needs bf16 k-idx [8q,+8) = chunk q (q=lane>>4) of row
    // r = w*64 + mt*16 + (lane&15); r&3 == lane&3.
    const int rsw   = ((lane >> 4) ^ (lane & 3)) << 3;
    const int a_off = (wm * 64 + (lane & 15)) * 32 + rsw;   // + mt*512
    const int b_off = (wn * 64 + (lane & 15)) * 32 + rsw;   // + nt*512

    f32x4 acc[4][4];
    #pragma unroll
    for (int i = 0; i < 4; ++i)
        #pragma unroll
        for (int j = 0; j < 4; ++j)
            acc[i][j] = (f32x4){0.f, 0.f, 0.f, 0.f};

    // two named staging sets (static indexing only — rule #20)
    float4 S0a[4], S0b[2], S1a[4], S1b[2];

    auto load_set = [&](float4 (&sa)[4], float4 (&sb)[2], size_t koff) {
        #pragma unroll
        for (int k = 0; k < 4; ++k)
            sa[k] = *(const float4*)(aptr + (size_t)(64 * k) * DIM + koff);
        sb[0] = *(const float4*)(bptr0 + koff);
        sb[1] = *(const float4*)(bptr1 + koff);
    };

    auto stage = [&](const float4 (&sa)[4], const float4 (&sb)[2], int buf) {
        #pragma unroll
        for (int k = 0; k < 4; ++k) {
            ushort4 p;
            p.x = f2bf(sa[k].x); p.y = f2bf(sa[k].y);
            p.z = f2bf(sa[k].z); p.w = f2bf(sa[k].w);
            *(ushort4*)&As[buf][wA + k * 2048] = p;
        }
        #pragma unroll
        for (int k = 0; k < 2; ++k) {
            ushort4 p;
            p.x = f2bf(sb[k].x); p.y = f2bf(sb[k].y);
            p.z = f2bf(sb[k].z); p.w = f2bf(sb[k].w);
            *(ushort4*)&Bs[buf][wA + k * 2048] = p;
        }
    };

    auto compute = [&](int buf) {
        bf16x8 afr[4], bfr[4];
        #pragma unroll
        for (int mt = 0; mt < 4; ++mt)
            afr[mt] = *(const bf16x8*)&As[buf][a_off + mt * 512];
        #pragma unroll
        for (int nt = 0; nt < 4; ++nt)
            bfr[nt] = *(const bf16x8*)&Bs[buf][b_off + nt * 512];
        #pragma unroll
        for (int mt = 0; mt < 4; ++mt)
            #pragma unroll
            for (int nt = 0; nt < 4; ++nt)
                acc[mt][nt] = __builtin_amdgcn_mfma_f32_16x16x32_bf16(
                    afr[mt], bfr[nt], acc[mt][nt], 0, 0, 0);
    };

    // raw barrier: drain LDS only — global loads stay in flight across it
    auto barrier = [&]() {
        asm volatile("s_waitcnt lgkmcnt(0)" ::: "memory");
        __builtin_amdgcn_s_barrier();
        __builtin_amdgcn_sched_barrier(0);
    };

    // ---- prologue: tiles 0,1 in flight; stage tile 0
    load_set(S0a, S0b, 0);        // tile 0 -> S0
    load_set(S1a, S1b, BK);       // tile 1 -> S1
    stage(S0a, S0b, 0);           // compiler waits only S0's loads
    barrier();

    size_t koff = 2 * BK;         // next issue: tile 2
    // paired main loop: iters 0..47 (24 pairs); iter 48 peeled
    for (int it = 0; it < KITERS - 1; it += 2) {
        // even iter: cur=0, issue tile it+2 -> S0, stage S1 (tile it+1) -> buf1
        load_set(S0a, S0b, koff); koff += BK;     // it<=46 < KITERS-2: always valid
        compute(0);
        stage(S1a, S1b, 1);
        barrier();
        // odd iter: cur=1, issue tile it+3 -> S1, stage S0 (tile it+2) -> buf0
        if (it + 1 < KITERS - 2) { load_set(S1a, S1b, koff); koff += BK; }
        compute(1);
        stage(S0a, S0b, 0);
        barrier();
    }
    compute(0);   // last iter (tile 48) from buf0

    // ---- epilogue: atomic-add partial 256x128 tile
    // C/D layout: col = lane&15, row = (lane>>4)*4 + reg
    const int orow0 = wm * 64 + (lane >> 4) * 4;
    const int ocol0 = col0 + wn * 64 + (lane & 15);
    #pragma unroll
    for (int mt = 0; mt < 4; ++mt) {
        #pragma unroll
        for (int nt = 0; nt < 4; ++nt) {
            const int ocol = ocol0 + nt * 16;
            if (ocol < NCLS) {
                #pragma unroll
                for (int e = 0; e < 4; ++e) {
                    const int orow = orow0 + mt * 16 + e;
                    atomicAdd(out + (size_t)orow * NCLS + ocol, acc[mt][nt][e]);
                }
            }
        }
    }
}

extern "C" void kernel_launch(void* const* d_in, const int* in_sizes, int n_in,
                              void* d_out, int out_size, void* d_ws, size_t ws_size,
                              hipStream_t stream) {
    const float* X = (const float*)d_in[0];   // [256, 150528]
    const float* W = (const float*)d_in[1];   // [1000, 150528]
    float* out = (float*)d_out;               // [256, 1000]

    hipMemsetAsync(out, 0, (size_t)out_size * sizeof(float), stream);

    dim3 grid(8, SPLIT);   // x: N tile, y: D chunk
    dim3 block(512);
    classifier_gemm<<<grid, block, 0, stream>>>(X, W, out);
}

// Round 3
// 1018.232 us; speedup vs baseline: 1.0157x; 1.0157x over previous
//
#include <hip/hip_runtime.h>
#include <hip/hip_bf16.h>

// GEMM: out[256,1000] = X[256,150528] * C[1000,150528]^T  (fp32 in/out)
// R5: 4-wave/256-thread blocks, 2 blocks/CU co-resident (two independent
// barrier groups), XCD swizzle so the 8 same-s blocks stream X through one
// XCD's L2. BM=256 BN=128 BK=32, depth-1 reg staging, XOR-swizzled bf16 LDS,
// split-K=96 with fp32 atomicAdd reduction.

#define BM 256
#define BN 128
#define BK 32
#define SPLIT 96
#define NCLS 1000
#define DIM 150528
#define DCHUNK (DIM / SPLIT)  // 1568
#define KITERS (DCHUNK / BK)  // 49 exact

typedef short bf16x8 __attribute__((ext_vector_type(8)));
typedef float f32x4 __attribute__((ext_vector_type(4)));

static __device__ __forceinline__ unsigned short f2bf(float f) {
    union { __hip_bfloat16 h; unsigned short u; } cv;
    cv.h = __float2bfloat16(f);
    return cv.u;
}

__global__ __launch_bounds__(256, 2) void classifier_gemm(
    const float* __restrict__ X, const float* __restrict__ W,
    float* __restrict__ out)
{
    // bf16 tiles, XOR-swizzled (no pad): row = 32 bf16 = 64 B = 4 chunks of 16 B,
    // chunk c of row r stored at c ^ (r & 3).  As 32 KB + Bs 16 KB = 48 KB.
    __shared__ __align__(16) unsigned short As[2][BM * BK];
    __shared__ __align__(16) unsigned short Bs[2][BN * BK];

    const int t    = threadIdx.x;
    const int lane = t & 63;
    const int wave = t >> 6;      // 0..3 (M quarter: 64 rows each)

    // ---- XCD swizzle: lin = (s%8) + 8*bj + 64*(s/8).
    // Default dispatch puts lin%8 on XCD lin%8, so all 8 bj-blocks of chunk s
    // land on XCD s%8 at adjacent slots -> they stream X[s] through that L2.
    const int lin = blockIdx.x;
    const int s   = ((lin >> 6) << 3) | (lin & 7);   // 0..95
    const int bj  = (lin >> 3) & 7;                  // 0..7
    const int col0 = bj * BN;
    const size_t d0 = (size_t)s * DCHUNK;

    // staging map: 8 lanes cover one 32-float row segment (16 B each)
    const int frow = t >> 3;        // 0..31
    const int fcol = (t & 7) * 4;   // float offset in row

    const float* aptr = X + (size_t)frow * DIM + d0 + fcol;   // rows frow+32k, k=0..7
    const float* bptr[4];                                     // rows col0+32k+frow, k=0..3
    #pragma unroll
    for (int k = 0; k < 4; ++k) {
        int br = col0 + 32 * k + frow;
        if (br >= NCLS) br = NCLS - 1;   // garbage cols >=1000 never stored
        bptr[k] = W + (size_t)br * DIM + d0 + fcol;
    }

    // ---- swizzled LDS offsets (ushort units) ----
    // write: chunk c=(t&7)>>1 of row r -> stored chunk c^(r&3); r&3 == frow&3.
    const int wsw = ((((t & 7) >> 1) ^ (frow & 3)) << 3) + (t & 1) * 4;
    const int wA  = frow * 32 + wsw;           // + k*1024 per 32-row group
    // read: frag chunk q=(lane>>4) of row base+(lane&15); row&3 == lane&3.
    const int rsw   = ((lane >> 4) ^ (lane & 3)) << 3;
    const int a_off = (wave * 64 + (lane & 15)) * 32 + rsw;   // + mt*512
    const int b_off = (lane & 15) * 32 + rsw;                 // + nt*512

    f32x4 acc[4][8];
    #pragma unroll
    for (int i = 0; i < 4; ++i)
        #pragma unroll
        for (int j = 0; j < 8; ++j)
            acc[i][j] = (f32x4){0.f, 0.f, 0.f, 0.f};

    // depth-1 staging registers: A 8 + B 4 = 12 float4
    float4 Sa[8], Sb[4];

    auto load_set = [&](size_t koff) {
        #pragma unroll
        for (int k = 0; k < 8; ++k)
            Sa[k] = *(const float4*)(aptr + (size_t)(32 * k) * DIM + koff);
        #pragma unroll
        for (int k = 0; k < 4; ++k)
            Sb[k] = *(const float4*)(bptr[k] + koff);
    };

    auto stage = [&](int buf) {
        #pragma unroll
        for (int k = 0; k < 8; ++k) {
            ushort4 p;
            p.x = f2bf(Sa[k].x); p.y = f2bf(Sa[k].y);
            p.z = f2bf(Sa[k].z); p.w = f2bf(Sa[k].w);
            *(ushort4*)&As[buf][wA + k * 1024] = p;
        }
        #pragma unroll
        for (int k = 0; k < 4; ++k) {
            ushort4 p;
            p.x = f2bf(Sb[k].x); p.y = f2bf(Sb[k].y);
            p.z = f2bf(Sb[k].z); p.w = f2bf(Sb[k].w);
            *(ushort4*)&Bs[buf][wA + k * 1024] = p;
        }
    };

    auto compute = [&](int buf) {
        bf16x8 afr[4], bfr[8];
        #pragma unroll
        for (int mt = 0; mt < 4; ++mt)
            afr[mt] = *(const bf16x8*)&As[buf][a_off + mt * 512];
        #pragma unroll
        for (int nt = 0; nt < 8; ++nt)
            bfr[nt] = *(const bf16x8*)&Bs[buf][b_off + nt * 512];
        #pragma unroll
        for (int mt = 0; mt < 4; ++mt)
            #pragma unroll
            for (int nt = 0; nt < 8; ++nt)
                acc[mt][nt] = __builtin_amdgcn_mfma_f32_16x16x32_bf16(
                    afr[mt], bfr[nt], acc[mt][nt], 0, 0, 0);
    };

    // raw barrier: drain LDS only — global loads stay in flight across it
    auto barrier = [&]() {
        asm volatile("s_waitcnt lgkmcnt(0)" ::: "memory");
        __builtin_amdgcn_s_barrier();
        __builtin_amdgcn_sched_barrier(0);
    };

    // ---- prologue: tile 0
    load_set(0);
    stage(0);
    barrier();

    size_t koff = BK;
    for (int it = 0; it < KITERS; ++it) {
        const int cur = it & 1;
        if (it + 1 < KITERS) { load_set(koff); koff += BK; }  // issue early
        compute(cur);                                          // covers latency
        if (it + 1 < KITERS) stage(cur ^ 1);                   // waits vmcnt via reg-deps
        barrier();
    }

    // ---- epilogue: atomic-add partial 256x128 tile
    // C/D layout: col = lane&15, row = (lane>>4)*4 + reg
    const int orow0 = wave * 64 + (lane >> 4) * 4;
    const int ocol0 = col0 + (lane & 15);
    #pragma unroll
    for (int mt = 0; mt < 4; ++mt) {
        #pragma unroll
        for (int nt = 0; nt < 8; ++nt) {
            const int ocol = ocol0 + nt * 16;
            if (ocol < NCLS) {
                #pragma unroll
                for (int e = 0; e < 4; ++e) {
                    const int orow = orow0 + mt * 16 + e;
                    atomicAdd(out + (size_t)orow * NCLS + ocol, acc[mt][nt][e]);
                }
            }
        }
    }
}

extern "C" void kernel_launch(void* const* d_in, const int* in_sizes, int n_in,
                              void* d_out, int out_size, void* d_ws, size_t ws_size,
                              hipStream_t stream) {
    const float* X = (const float*)d_in[0];   // [256, 150528]
    const float* W = (const float*)d_in[1];   // [1000, 150528]
    float* out = (float*)d_out;               // [256, 1000]

    hipMemsetAsync(out, 0, (size_t)out_size * sizeof(float), stream);

    dim3 grid(8 * SPLIT);   // linear; decoded via XCD swizzle in-kernel
    dim3 block(256);
    classifier_gemm<<<grid, block, 0, stream>>>(X, W, out);
}